// Round 14
// baseline (129.147 us; speedup 1.0000x reference)
//
#include <hip/hip_runtime.h>

#define N_NODES 100000
#define D_FEAT 128
#define CLASSES 64
#define N_EDGES 800000
#define DUMMY N_NODES        // zero row in Y table
#define NPP 64               // nodes per partition
#define NPART 1563           // ceil(N_NODES / NPP)
#define PCAP 768             // per-partition cap: mean 512, +11 sigma
#define CBKT 64              // coarse buckets (dst>>11), 49 used
#define CCAP 18432           // per-bucket cap: mean 16.3k
#define BPB 8                // blocks per bucket in binB
#define NSTRIP (N_NODES / 16)  // 6250
#define GEMM_BLOCKS 782

typedef short bf16x8 __attribute__((ext_vector_type(8)));
typedef float f32x4 __attribute__((ext_vector_type(4)));
typedef float fvec4 __attribute__((ext_vector_type(4)));

static __device__ __forceinline__ unsigned short f32_to_bf16(float f) {
    unsigned int u = __float_as_uint(f);
    u += 0x7FFFu + ((u >> 16) & 1u);  // round-to-nearest-even
    return (unsigned short)(u >> 16);
}
static __device__ __forceinline__ float bf16_lo(unsigned int u) {
    return __uint_as_float(u << 16);
}
static __device__ __forceinline__ float bf16_hi(unsigned int u) {
    return __uint_as_float(u & 0xFFFF0000u);
}

// Kernel 1: zero coarse+fine tails and the dummy Y row.
__global__ void zq_kernel(int* __restrict__ tails, unsigned int* __restrict__ yb) {
    int i = blockIdx.x * blockDim.x + threadIdx.x;
    if (i < 1024 + NPART * 16) tails[i] = 0;
    if (i < 32) yb[(size_t)DUMMY * 32 + i] = 0;
}

// Kernel 2: coarse multisplit. Tiles of 256 edges; LDS histogram over 64
// buckets; ONE global tail atomic per (tile,bucket); ranked scatter writes
// avg-5-consecutive dwords per bucket stream -> queue lines fill fast
// (kills the R7-R13 partial-line RFO/writeback round-trips: random 4B
// stores cost ~128B of HBM traffic each when lines can't stay resident).
__global__ __launch_bounds__(256) void binA_kernel(
        const int* __restrict__ src, const int* __restrict__ dst,
        int* __restrict__ ctail, unsigned int* __restrict__ cbuf) {
    __shared__ int hist[CBKT];
    __shared__ int base[CBKT];
    for (int t0 = blockIdx.x * 256; t0 < N_EDGES; t0 += gridDim.x * 256) {
        int e = t0 + threadIdx.x;
        bool valid = e < N_EDGES;
        int d = 0, s = 0;
        if (valid) { d = dst[e]; s = src[e]; }
        int bk = d >> 11;
        if (threadIdx.x < CBKT) hist[threadIdx.x] = 0;
        __syncthreads();
        int rank = 0;
        if (valid) rank = atomicAdd(&hist[bk], 1);
        __syncthreads();
        if (threadIdx.x < CBKT) {
            int h = hist[threadIdx.x];
            base[threadIdx.x] = h ? atomicAdd(&ctail[threadIdx.x * 16], h) : 0;
        }
        __syncthreads();
        if (valid) {
            int pos = base[bk] + rank;
            if (pos < CCAP)
                cbuf[(size_t)bk * CCAP + pos] =
                    ((unsigned int)(d & 2047) << 17) | (unsigned int)s;
        }
        __syncthreads();
    }
}

// Kernel 3: fine multisplit within each coarse bucket. 32 bins; global fine
// queue id (bk<<5)|bin == dst>>6 == partition id. Entry format matches accum:
// (dloc<<17)|src.
__global__ __launch_bounds__(256) void binB_kernel(
        const int* __restrict__ ctail, const unsigned int* __restrict__ cbuf,
        int* __restrict__ ftail, unsigned int* __restrict__ fbuf) {
    __shared__ int hist[32];
    __shared__ int base[32];
    const int bk = blockIdx.x / BPB;
    const int sub = blockIdx.x % BPB;
    const int cnt = min(ctail[bk * 16], CCAP);
    const unsigned int* cb = cbuf + (size_t)bk * CCAP;
    for (int t0 = sub * 256; t0 < cnt; t0 += BPB * 256) {
        int i = t0 + threadIdx.x;
        bool valid = i < cnt;
        unsigned int ent = valid ? cb[i] : 0u;
        int d11 = (int)(ent >> 17);
        int bin = d11 >> 6;  // 0..31
        if (threadIdx.x < 32) hist[threadIdx.x] = 0;
        __syncthreads();
        int rank = 0;
        if (valid) rank = atomicAdd(&hist[bin], 1);
        __syncthreads();
        if (threadIdx.x < 32) {
            int h = hist[threadIdx.x];
            int qid = (bk << 5) | threadIdx.x;
            base[threadIdx.x] = h ? atomicAdd(&ftail[qid * 16], h) : 0;
        }
        __syncthreads();
        if (valid) {
            int pos = base[bin] + rank;
            if (pos < PCAP) {
                int qid = (bk << 5) | bin;
                fbuf[(size_t)qid * PCAP + pos] =
                    ((unsigned int)(d11 & 63) << 17) | (ent & 0x1FFFFu);
            }
        }
        __syncthreads();
    }
}

// Kernel 4: MFMA GEMM Y = X @ W (pre-bias), bf16, 2 strips/wave, batched
// nontemporal loads. Y packed so dword t = classes (t, t+32).
__global__ __launch_bounds__(256) void gemm_kernel(
        const float* __restrict__ x, const float* __restrict__ W,
        unsigned short* __restrict__ ybu) {
    __shared__ unsigned int Wf[4 * 4 * 64 * 4];  // 16 KB
    for (int idx = threadIdx.x; idx < 4096; idx += 256) {
        int kk = idx >> 10, n = (idx >> 8) & 3, l = (idx >> 2) & 63, r = idx & 3;
        int k = kk * 32 + ((l >> 4) << 3) + 2 * r;
        int c = n * 16 + (l & 15);
        unsigned int lov = f32_to_bf16(W[k * CLASSES + c]);
        unsigned int hiv = f32_to_bf16(W[(k + 1) * CLASSES + c]);
        Wf[idx] = lov | (hiv << 16);
    }
    __syncthreads();

    const int wave = threadIdx.x >> 6;
    const int lane = threadIdx.x & 63;
    const int row_in = lane & 15;
    const int kb = (lane >> 4) << 3;

    const int widx = blockIdx.x * 4 + wave;
    if (widx >= NSTRIP / 2) return;

    const float* xr0 = x + (size_t)(widx * 32 + row_in) * D_FEAT + kb;
    const float* xr1 = xr0 + 16 * D_FEAT;

    fvec4 v[16];
#pragma unroll
    for (int kk = 0; kk < 4; ++kk) {
        v[kk * 2 + 0] = __builtin_nontemporal_load((const fvec4*)(xr0 + kk * 32));
        v[kk * 2 + 1] = __builtin_nontemporal_load((const fvec4*)(xr0 + kk * 32 + 4));
        v[8 + kk * 2 + 0] = __builtin_nontemporal_load((const fvec4*)(xr1 + kk * 32));
        v[8 + kk * 2 + 1] = __builtin_nontemporal_load((const fvec4*)(xr1 + kk * 32 + 4));
    }

    bf16x8 af0[4], af1[4];
#pragma unroll
    for (int kk = 0; kk < 4; ++kk) {
        fvec4 a = v[kk * 2], c = v[kk * 2 + 1];
        bf16x8 t0;
        t0[0] = (short)f32_to_bf16(a.x); t0[1] = (short)f32_to_bf16(a.y);
        t0[2] = (short)f32_to_bf16(a.z); t0[3] = (short)f32_to_bf16(a.w);
        t0[4] = (short)f32_to_bf16(c.x); t0[5] = (short)f32_to_bf16(c.y);
        t0[6] = (short)f32_to_bf16(c.z); t0[7] = (short)f32_to_bf16(c.w);
        af0[kk] = t0;
        fvec4 d = v[8 + kk * 2], e = v[8 + kk * 2 + 1];
        bf16x8 t1;
        t1[0] = (short)f32_to_bf16(d.x); t1[1] = (short)f32_to_bf16(d.y);
        t1[2] = (short)f32_to_bf16(d.z); t1[3] = (short)f32_to_bf16(d.w);
        t1[4] = (short)f32_to_bf16(e.x); t1[5] = (short)f32_to_bf16(e.y);
        t1[6] = (short)f32_to_bf16(e.z); t1[7] = (short)f32_to_bf16(e.w);
        af1[kk] = t1;
    }

    f32x4 acc0[4] = {{0.f,0.f,0.f,0.f},{0.f,0.f,0.f,0.f},{0.f,0.f,0.f,0.f},{0.f,0.f,0.f,0.f}};
    f32x4 acc1[4] = {{0.f,0.f,0.f,0.f},{0.f,0.f,0.f,0.f},{0.f,0.f,0.f,0.f},{0.f,0.f,0.f,0.f}};
#pragma unroll
    for (int n = 0; n < 4; ++n) {
#pragma unroll
        for (int kk = 0; kk < 4; ++kk) {
            bf16x8 bfr = *(const bf16x8*)&Wf[((kk * 4 + n) * 64 + lane) * 4];
            acc0[n] = __builtin_amdgcn_mfma_f32_16x16x32_bf16(af0[kk], bfr, acc0[n], 0, 0, 0);
            acc1[n] = __builtin_amdgcn_mfma_f32_16x16x32_bf16(af1[kk], bfr, acc1[n], 0, 0, 0);
        }
    }

    unsigned short* yr0 = ybu + (size_t)(widx * 2) * 16 * CLASSES;
    unsigned short* yr1 = yr0 + 16 * CLASSES;
#pragma unroll
    for (int n = 0; n < 4; ++n) {
        int c = n * 16 + (lane & 15);
        int pos = ((c & 31) << 1) + (c >> 5);
#pragma unroll
        for (int r = 0; r < 4; ++r) {
            yr0[((lane >> 4) * 4 + r) * CLASSES + pos] = f32_to_bf16(acc0[n][r]);
            yr1[((lane >> 4) * 4 + r) * CLASSES + pos] = f32_to_bf16(acc1[n][r]);
        }
    }
}

// Kernel 5: one block per 64-node partition. Stage the partition's (single,
// contiguous) fine queue into LDS, CSR-sort, register gather (half-wave per
// node, 4 interleaved, branch-free DUMMY padding), epilogue adds self + bias.
__global__ __launch_bounds__(256) void accum_kernel(
        const unsigned int* __restrict__ yb, const int* __restrict__ ftail,
        const unsigned int* __restrict__ fbuf, const float* __restrict__ b,
        float* __restrict__ out) {
    __shared__ unsigned int ent[PCAP];
    __shared__ int sorted_s[PCAP];
    __shared__ int cnt_s[NPP], start_s[NPP], cursor_s[NPP];

    const int tid = threadIdx.x;
    const int p = blockIdx.x;

    if (tid < NPP) cnt_s[tid] = 0;
    __syncthreads();

    const int tot = min(ftail[p * 16], PCAP);
    const unsigned int* fq = fbuf + (size_t)p * PCAP;
    for (int i = tid; i < tot; i += 256) ent[i] = fq[i];
    __syncthreads();

    for (int i = tid; i < tot; i += 256) atomicAdd(&cnt_s[ent[i] >> 17], 1);
    __syncthreads();

    if (tid < 64) {  // wave 0: prefix scan over 64 node counts
        int v = cnt_s[tid];
        int incl = v;
#pragma unroll
        for (int o = 1; o < 64; o <<= 1) {
            int u = __shfl_up(incl, o, 64);
            if (tid >= o) incl += u;
        }
        start_s[tid] = incl - v;
        cursor_s[tid] = incl - v;
    }
    __syncthreads();

    for (int i = tid; i < tot; i += 256) {
        unsigned int e = ent[i];
        int pos = atomicAdd(&cursor_s[e >> 17], 1);
        sorted_s[pos] = (int)(e & 0x1FFFFu);
    }
    __syncthreads();

    const int hw = tid >> 5;   // half-wave 0..7
    const int t = tid & 31;
    const float b0 = b[t], b1 = b[t + 32];

#pragma unroll
    for (int rr = 0; rr < 2; ++rr) {
        const int r0 = hw * 8 + rr * 4;
        int deg0 = cnt_s[r0], st0 = start_s[r0];
        int deg1 = cnt_s[r0 + 1], st1 = start_s[r0 + 1];
        int deg2 = cnt_s[r0 + 2], st2 = start_s[r0 + 2];
        int deg3 = cnt_s[r0 + 3], st3 = start_s[r0 + 3];
        int dmax = max(max(deg0, deg1), max(deg2, deg3));

        float2 a0 = {0.f, 0.f}, a1 = {0.f, 0.f}, a2 = {0.f, 0.f}, a3 = {0.f, 0.f};

        for (int cb = 0; cb < dmax; cb += 32) {
            int i0 = (cb + t < deg0) ? sorted_s[st0 + cb + t] : DUMMY;
            int i1 = (cb + t < deg1) ? sorted_s[st1 + cb + t] : DUMMY;
            int i2 = (cb + t < deg2) ? sorted_s[st2 + cb + t] : DUMMY;
            int i3 = (cb + t < deg3) ? sorted_s[st3 + cb + t] : DUMMY;
            int lim = min(32, dmax - cb);
#pragma unroll 4
            for (int j = 0; j < lim; ++j) {
                int s0 = __shfl(i0, j, 32);
                int s1 = __shfl(i1, j, 32);
                int s2 = __shfl(i2, j, 32);
                int s3 = __shfl(i3, j, 32);
                unsigned int y0 = yb[(size_t)s0 * 32 + t];
                unsigned int y1 = yb[(size_t)s1 * 32 + t];
                unsigned int y2 = yb[(size_t)s2 * 32 + t];
                unsigned int y3 = yb[(size_t)s3 * 32 + t];
                a0.x += bf16_lo(y0); a0.y += bf16_hi(y0);
                a1.x += bf16_lo(y1); a1.y += bf16_hi(y1);
                a2.x += bf16_lo(y2); a2.y += bf16_hi(y2);
                a3.x += bf16_lo(y3); a3.y += bf16_hi(y3);
            }
        }

#pragma unroll
        for (int k = 0; k < 4; ++k) {
            int node = p * NPP + r0 + k;
            if (node < N_NODES) {
                float2 a = (k == 0) ? a0 : (k == 1) ? a1 : (k == 2) ? a2 : a3;
                unsigned int u = yb[(size_t)node * 32 + t];
                out[(size_t)node * 64 + t] = a.x + bf16_lo(u) + b0;
                out[(size_t)node * 64 + t + 32] = a.y + bf16_hi(u) + b1;
            }
        }
    }
}

extern "C" void kernel_launch(void* const* d_in, const int* in_sizes, int n_in,
                              void* d_out, int out_size, void* d_ws, size_t ws_size,
                              hipStream_t stream) {
    const float* x = (const float*)d_in[0];
    const int* edge = (const int*)d_in[1];  // [2, N_EDGES] int32
    const float* W = (const float*)d_in[2];
    const float* b = (const float*)d_in[3];
    float* out = (float*)d_out;

    // workspace layout (~23 MB):
    int* ctail = (int*)d_ws;                         // 64*16 ints (line-padded)
    int* ftail = ctail + 1024;                       // 1563*16 -> pad 25088 ints
    unsigned int* cbuf = (unsigned int*)(ftail + 25088);   // 64*18432 dw = 4.7 MB
    unsigned int* fbuf = cbuf + (size_t)CBKT * CCAP;       // 1563*768 dw = 4.8 MB
    unsigned int* yb = fbuf + (size_t)NPART * PCAP;        // 100001*32 dw = 12.8 MB
    unsigned short* ybu = (unsigned short*)yb;

    const int* src = edge;
    const int* dst = edge + N_EDGES;

    zq_kernel<<<(1024 + NPART * 16 + 255) / 256, 256, 0, stream>>>(ctail, yb);
    binA_kernel<<<512, 256, 0, stream>>>(src, dst, ctail, cbuf);
    binB_kernel<<<49 * BPB, 256, 0, stream>>>(ctail, cbuf, ftail, fbuf);
    gemm_kernel<<<GEMM_BLOCKS, 256, 0, stream>>>(x, W, ybu);
    accum_kernel<<<NPART, 256, 0, stream>>>(yb, ftail, fbuf, b, out);
}

// Round 15
// 80.658 us; speedup vs baseline: 1.6012x; 1.6012x over previous
//
#include <hip/hip_runtime.h>

#define N_NODES 100000
#define D_FEAT 128
#define CLASSES 64
#define N_EDGES 800000
#define DUMMY N_NODES        // zero row in Y table
#define NPP 64               // nodes per partition
#define NPART 1563           // ceil(N_NODES / NPP)
#define PCAP 768             // per-partition cap: mean 512, +11 sigma
#define CBKT 64              // coarse buckets (dst>>11), 49 used
#define CCAP 18432           // per-bucket cap: mean 16.3k, +16 sigma
#define NSTRIP (N_NODES / 16)  // 6250
#define GEMM_BLOCKS 782
#define BINA_BLOCKS 782
#define TILE_A 1024
#define NTILE_A 782          // ceil(N_EDGES / TILE_A)
#define BPB 16               // binB blocks per bucket

typedef short bf16x8 __attribute__((ext_vector_type(8)));
typedef float f32x4 __attribute__((ext_vector_type(4)));
typedef float fvec4 __attribute__((ext_vector_type(4)));

static __device__ __forceinline__ unsigned short f32_to_bf16(float f) {
    unsigned int u = __float_as_uint(f);
    u += 0x7FFFu + ((u >> 16) & 1u);  // round-to-nearest-even
    return (unsigned short)(u >> 16);
}
static __device__ __forceinline__ float bf16_lo(unsigned int u) {
    return __uint_as_float(u << 16);
}
static __device__ __forceinline__ float bf16_hi(unsigned int u) {
    return __uint_as_float(u & 0xFFFF0000u);
}

// Kernel 1: zero coarse+fine tails and the dummy Y row.
__global__ void zq_kernel(int* __restrict__ tails, unsigned int* __restrict__ yb) {
    int i = blockIdx.x * blockDim.x + threadIdx.x;
    if (i < 1024 + NPART * 16 + 80) tails[i] = 0;
    if (i < 32) yb[(size_t)DUMMY * 32 + i] = 0;
}

// Kernel 2 (fused): blocks [0,GEMM_BLOCKS) = MFMA GEMM Y=X@W (2 strips/wave,
// batched nontemporal loads). Blocks [GEMM_BLOCKS,+BINA_BLOCKS) = coarse
// multisplit, RESTRUCTURED from R14: 1024-edge tiles (4 edges/thread),
// per-wave private histograms (4x less LDS-atomic contention), 3 barriers
// per tile instead of 16 (R14 binA: VALUBusy 0.6%, 18% occ = barrier/atomic
// serialization, NOT bandwidth). gemm's HBM stream hides binA's latency.
__global__ __launch_bounds__(256) void fused_gemm_binA_kernel(
        const float* __restrict__ x, const float* __restrict__ W,
        const int* __restrict__ src, const int* __restrict__ dst,
        int* __restrict__ ctail, unsigned int* __restrict__ cbuf,
        unsigned short* __restrict__ ybu) {
    __shared__ unsigned int Wf[4096];   // 16 KB (gemm role)
    __shared__ int hist[4][CBKT];       // per-wave hist (binA role)
    __shared__ int wof[4][CBKT];
    __shared__ int base[CBKT];

    if (blockIdx.x >= GEMM_BLOCKS) {
        const int tid = threadIdx.x;
        const int wv = tid >> 6;
        for (int tile = blockIdx.x - GEMM_BLOCKS; tile < NTILE_A; tile += BINA_BLOCKS) {
            const int e0 = tile * TILE_A;
            int d[4], s[4], bk[4], rk[4];
            bool val[4];
#pragma unroll
            for (int j = 0; j < 4; ++j) {
                int e = e0 + j * 256 + tid;
                val[j] = e < N_EDGES;
                int ee = val[j] ? e : 0;
                d[j] = __builtin_nontemporal_load(dst + ee);
                s[j] = __builtin_nontemporal_load(src + ee);
                bk[j] = d[j] >> 11;
            }
            hist[tid >> 6][tid & 63] = 0;
            __syncthreads();
#pragma unroll
            for (int j = 0; j < 4; ++j)
                if (val[j]) rk[j] = atomicAdd(&hist[wv][bk[j]], 1);
            __syncthreads();
            if (tid < CBKT) {
                int h0 = hist[0][tid], h1 = hist[1][tid];
                int h2 = hist[2][tid], h3 = hist[3][tid];
                int tot = h0 + h1 + h2 + h3;
                base[tid] = tot ? atomicAdd(&ctail[tid * 16], tot) : 0;
                wof[0][tid] = 0; wof[1][tid] = h0;
                wof[2][tid] = h0 + h1; wof[3][tid] = h0 + h1 + h2;
            }
            __syncthreads();
#pragma unroll
            for (int j = 0; j < 4; ++j) {
                if (val[j]) {
                    int pos = base[bk[j]] + wof[wv][bk[j]] + rk[j];
                    if (pos < CCAP)
                        cbuf[(size_t)bk[j] * CCAP + pos] =
                            ((unsigned int)(d[j] & 2047) << 17) | (unsigned int)s[j];
                }
            }
            // no 4th barrier needed: next clear races only with scatter
            // (disjoint LDS), ranks are behind the next barrier.
        }
        return;
    }

    // ---- gemm role ----
    for (int idx = threadIdx.x; idx < 4096; idx += 256) {
        int kk = idx >> 10, n = (idx >> 8) & 3, l = (idx >> 2) & 63, r = idx & 3;
        int k = kk * 32 + ((l >> 4) << 3) + 2 * r;
        int c = n * 16 + (l & 15);
        unsigned int lov = f32_to_bf16(W[k * CLASSES + c]);
        unsigned int hiv = f32_to_bf16(W[(k + 1) * CLASSES + c]);
        Wf[idx] = lov | (hiv << 16);
    }
    __syncthreads();

    const int wave = threadIdx.x >> 6;
    const int lane = threadIdx.x & 63;
    const int row_in = lane & 15;
    const int kb = (lane >> 4) << 3;

    const int widx = blockIdx.x * 4 + wave;
    if (widx >= NSTRIP / 2) return;

    const float* xr0 = x + (size_t)(widx * 32 + row_in) * D_FEAT + kb;
    const float* xr1 = xr0 + 16 * D_FEAT;

    fvec4 v[16];
#pragma unroll
    for (int kk = 0; kk < 4; ++kk) {
        v[kk * 2 + 0] = __builtin_nontemporal_load((const fvec4*)(xr0 + kk * 32));
        v[kk * 2 + 1] = __builtin_nontemporal_load((const fvec4*)(xr0 + kk * 32 + 4));
        v[8 + kk * 2 + 0] = __builtin_nontemporal_load((const fvec4*)(xr1 + kk * 32));
        v[8 + kk * 2 + 1] = __builtin_nontemporal_load((const fvec4*)(xr1 + kk * 32 + 4));
    }

    bf16x8 af0[4], af1[4];
#pragma unroll
    for (int kk = 0; kk < 4; ++kk) {
        fvec4 a = v[kk * 2], c = v[kk * 2 + 1];
        bf16x8 t0;
        t0[0] = (short)f32_to_bf16(a.x); t0[1] = (short)f32_to_bf16(a.y);
        t0[2] = (short)f32_to_bf16(a.z); t0[3] = (short)f32_to_bf16(a.w);
        t0[4] = (short)f32_to_bf16(c.x); t0[5] = (short)f32_to_bf16(c.y);
        t0[6] = (short)f32_to_bf16(c.z); t0[7] = (short)f32_to_bf16(c.w);
        af0[kk] = t0;
        fvec4 d = v[8 + kk * 2], e = v[8 + kk * 2 + 1];
        bf16x8 t1;
        t1[0] = (short)f32_to_bf16(d.x); t1[1] = (short)f32_to_bf16(d.y);
        t1[2] = (short)f32_to_bf16(d.z); t1[3] = (short)f32_to_bf16(d.w);
        t1[4] = (short)f32_to_bf16(e.x); t1[5] = (short)f32_to_bf16(e.y);
        t1[6] = (short)f32_to_bf16(e.z); t1[7] = (short)f32_to_bf16(e.w);
        af1[kk] = t1;
    }

    f32x4 acc0[4] = {{0.f,0.f,0.f,0.f},{0.f,0.f,0.f,0.f},{0.f,0.f,0.f,0.f},{0.f,0.f,0.f,0.f}};
    f32x4 acc1[4] = {{0.f,0.f,0.f,0.f},{0.f,0.f,0.f,0.f},{0.f,0.f,0.f,0.f},{0.f,0.f,0.f,0.f}};
#pragma unroll
    for (int n = 0; n < 4; ++n) {
#pragma unroll
        for (int kk = 0; kk < 4; ++kk) {
            bf16x8 bfr = *(const bf16x8*)&Wf[((kk * 4 + n) * 64 + lane) * 4];
            acc0[n] = __builtin_amdgcn_mfma_f32_16x16x32_bf16(af0[kk], bfr, acc0[n], 0, 0, 0);
            acc1[n] = __builtin_amdgcn_mfma_f32_16x16x32_bf16(af1[kk], bfr, acc1[n], 0, 0, 0);
        }
    }

    unsigned short* yr0 = ybu + (size_t)(widx * 2) * 16 * CLASSES;
    unsigned short* yr1 = yr0 + 16 * CLASSES;
#pragma unroll
    for (int n = 0; n < 4; ++n) {
        int c = n * 16 + (lane & 15);
        int pos = ((c & 31) << 1) + (c >> 5);
#pragma unroll
        for (int r = 0; r < 4; ++r) {
            yr0[((lane >> 4) * 4 + r) * CLASSES + pos] = f32_to_bf16(acc0[n][r]);
            yr1[((lane >> 4) * 4 + r) * CLASSES + pos] = f32_to_bf16(acc1[n][r]);
        }
    }
}

// Kernel 3: fine multisplit, same per-wave-hist restructure. 16 blocks per
// coarse bucket, 1024-entry tiles, 4 entries/thread.
__global__ __launch_bounds__(256) void binB_kernel(
        const int* __restrict__ ctail, const unsigned int* __restrict__ cbuf,
        int* __restrict__ ftail, unsigned int* __restrict__ fbuf) {
    __shared__ int hist[4][32];
    __shared__ int wof[4][32];
    __shared__ int base[32];
    const int tid = threadIdx.x;
    const int wv = tid >> 6;
    const int bk = blockIdx.x / BPB;
    const int sub = blockIdx.x % BPB;
    const int cnt = min(ctail[bk * 16], CCAP);
    const unsigned int* cb = cbuf + (size_t)bk * CCAP;

    for (int t0 = sub * 1024; t0 < cnt; t0 += BPB * 1024) {
        unsigned int ent[4];
        int bin[4], rk[4];
        bool val[4];
#pragma unroll
        for (int j = 0; j < 4; ++j) {
            int i = t0 + j * 256 + tid;
            val[j] = i < cnt;
            ent[j] = val[j] ? cb[i] : 0u;
            bin[j] = (int)(ent[j] >> 23);  // d11>>6, d11 = ent>>17 (11 bits)
        }
        if (tid < 128) hist[tid >> 5][tid & 31] = 0;
        __syncthreads();
#pragma unroll
        for (int j = 0; j < 4; ++j)
            if (val[j]) rk[j] = atomicAdd(&hist[wv][bin[j]], 1);
        __syncthreads();
        if (tid < 32) {
            int h0 = hist[0][tid], h1 = hist[1][tid];
            int h2 = hist[2][tid], h3 = hist[3][tid];
            int tot = h0 + h1 + h2 + h3;
            int qid = (bk << 5) | tid;
            base[tid] = tot ? atomicAdd(&ftail[qid * 16], tot) : 0;
            wof[0][tid] = 0; wof[1][tid] = h0;
            wof[2][tid] = h0 + h1; wof[3][tid] = h0 + h1 + h2;
        }
        __syncthreads();
#pragma unroll
        for (int j = 0; j < 4; ++j) {
            if (val[j]) {
                int pos = base[bin[j]] + wof[wv][bin[j]] + rk[j];
                if (pos < PCAP) {
                    int qid = (bk << 5) | bin[j];
                    int d11 = (int)(ent[j] >> 17);
                    fbuf[(size_t)qid * PCAP + pos] =
                        ((unsigned int)(d11 & 63) << 17) | (ent[j] & 0x1FFFFu);
                }
            }
        }
        __syncthreads();
    }
}

// Kernel 4: one block per 64-node partition. Stage fine queue into LDS,
// CSR-sort, register gather with 8 nodes interleaved per half-wave
// (8 loads in flight vs R14's 4), epilogue adds self + bias.
__global__ __launch_bounds__(256) void accum_kernel(
        const unsigned int* __restrict__ yb, const int* __restrict__ ftail,
        const unsigned int* __restrict__ fbuf, const float* __restrict__ b,
        float* __restrict__ out) {
    __shared__ unsigned int ent[PCAP];
    __shared__ int sorted_s[PCAP];
    __shared__ int cnt_s[NPP], start_s[NPP], cursor_s[NPP];

    const int tid = threadIdx.x;
    const int p = blockIdx.x;

    if (tid < NPP) cnt_s[tid] = 0;
    __syncthreads();

    const int tot = min(ftail[p * 16], PCAP);
    const unsigned int* fq = fbuf + (size_t)p * PCAP;
    for (int i = tid; i < tot; i += 256) ent[i] = fq[i];
    __syncthreads();

    for (int i = tid; i < tot; i += 256) atomicAdd(&cnt_s[ent[i] >> 17], 1);
    __syncthreads();

    if (tid < 64) {
        int v = cnt_s[tid];
        int incl = v;
#pragma unroll
        for (int o = 1; o < 64; o <<= 1) {
            int u = __shfl_up(incl, o, 64);
            if (tid >= o) incl += u;
        }
        start_s[tid] = incl - v;
        cursor_s[tid] = incl - v;
    }
    __syncthreads();

    for (int i = tid; i < tot; i += 256) {
        unsigned int e = ent[i];
        int pos = atomicAdd(&cursor_s[e >> 17], 1);
        sorted_s[pos] = (int)(e & 0x1FFFFu);
    }
    __syncthreads();

    const int hw = tid >> 5;   // half-wave 0..7, owns local nodes hw*8..hw*8+7
    const int t = tid & 31;
    const float b0 = b[t], b1 = b[t + 32];

    const int r0 = hw * 8;
    int deg[8], st[8];
#pragma unroll
    for (int k = 0; k < 8; ++k) { deg[k] = cnt_s[r0 + k]; st[k] = start_s[r0 + k]; }
    int dmax = 0;
#pragma unroll
    for (int k = 0; k < 8; ++k) dmax = max(dmax, deg[k]);

    float2 a[8];
#pragma unroll
    for (int k = 0; k < 8; ++k) a[k] = make_float2(0.f, 0.f);

    for (int cb = 0; cb < dmax; cb += 32) {
        int idx[8];
#pragma unroll
        for (int k = 0; k < 8; ++k)
            idx[k] = (cb + t < deg[k]) ? sorted_s[st[k] + cb + t] : DUMMY;
        int lim = min(32, dmax - cb);
#pragma unroll 2
        for (int j = 0; j < lim; ++j) {
#pragma unroll
            for (int k = 0; k < 8; ++k) {
                int sk = __shfl(idx[k], j, 32);
                unsigned int yk = yb[(size_t)sk * 32 + t];
                a[k].x += bf16_lo(yk);
                a[k].y += bf16_hi(yk);
            }
        }
    }

#pragma unroll
    for (int k = 0; k < 8; ++k) {
        int node = p * NPP + r0 + k;
        if (node < N_NODES) {
            unsigned int u = yb[(size_t)node * 32 + t];
            out[(size_t)node * 64 + t] = a[k].x + bf16_lo(u) + b0;
            out[(size_t)node * 64 + t + 32] = a[k].y + bf16_hi(u) + b1;
        }
    }
}

extern "C" void kernel_launch(void* const* d_in, const int* in_sizes, int n_in,
                              void* d_out, int out_size, void* d_ws, size_t ws_size,
                              hipStream_t stream) {
    const float* x = (const float*)d_in[0];
    const int* edge = (const int*)d_in[1];  // [2, N_EDGES] int32
    const float* W = (const float*)d_in[2];
    const float* b = (const float*)d_in[3];
    float* out = (float*)d_out;

    // workspace layout (~23 MB):
    int* ctail = (int*)d_ws;                               // 64*16 ints
    int* ftail = ctail + 1024;                             // 1563*16 -> pad 25088
    unsigned int* cbuf = (unsigned int*)(ftail + 25088);   // 64*18432 dw = 4.7 MB
    unsigned int* fbuf = cbuf + (size_t)CBKT * CCAP;       // 1563*768 dw = 4.8 MB
    unsigned int* yb = fbuf + (size_t)NPART * PCAP;        // 100001*32 dw = 12.8 MB
    unsigned short* ybu = (unsigned short*)yb;

    const int* src = edge;
    const int* dst = edge + N_EDGES;

    zq_kernel<<<(1024 + NPART * 16 + 80 + 255) / 256, 256, 0, stream>>>(ctail, yb);
    fused_gemm_binA_kernel<<<GEMM_BLOCKS + BINA_BLOCKS, 256, 0, stream>>>(
        x, W, src, dst, ctail, cbuf, ybu);
    binB_kernel<<<49 * BPB, 256, 0, stream>>>(ctail, cbuf, ftail, fbuf);
    accum_kernel<<<NPART, 256, 0, stream>>>(yb, ftail, fbuf, b, out);
}